// Round 6
// baseline (182.214 us; speedup 1.0000x reference)
//
#include <hip/hip_runtime.h>
#include <stdint.h>

typedef unsigned long long u64;
typedef unsigned int u32;

#define BATCH 32
#define NCH 84
#define NA 8400
#define NCLS 80
#define TOPK 1000
#define MAXDET 300
#define CONF 0.25f
#define IOU_T 0.7f
#define MAX_WH 7680.0f
#define IMG_SZ 640.0f
#define NT 1024
#define KPT 9            // ceil(NA / NT)
#define NCOPY 8          // privatized histogram copies (fallback path)
#define HPAD 260         // 16B-aligned rows, bank-staggered copies

__device__ __constant__ float coco_map_f[NCLS] = {
    1,2,3,4,5,6,7,8,9,10,11,13,14,15,16,17,18,19,20,21,22,23,24,25,27,28,
    31,32,33,34,35,36,37,38,39,40,41,42,43,44,46,47,48,49,50,51,52,53,54,
    55,56,57,58,59,60,61,62,63,64,65,67,70,72,73,74,75,76,77,78,79,80,81,
    82,84,85,86,87,88,89,90};

__device__ inline u64 shflx64(u64 v, int m) {
    int lo = __shfl_xor((int)(u32)(v & 0xFFFFFFFFull), m, 64);
    int hi = __shfl_xor((int)(u32)(v >> 32), m, 64);
    return ((u64)(u32)hi << 32) | (u32)lo;
}

// ---- K1: decode, direct coalesced reads (no LDS) ----------------------------
// key = score_bits<<21 | (16383-a)<<7 | label   (order: score desc, anchor asc)
__global__ __launch_bounds__(256)
void decode_kernel(const float* __restrict__ preds,
                   u64* __restrict__ keys,
                   float4* __restrict__ boxes) {
    const int b = blockIdx.y;
    const int a = blockIdx.x * 256 + threadIdx.x;
    const bool live = (a < NA);
    const int ac = live ? a : (NA - 1);               // clamp: keep loads in-bounds
    const float* p = preds + (size_t)b * NCH * NA + ac;

    float bx = p[0];
    float by = p[(size_t)1 * NA];
    float bw = p[(size_t)2 * NA];
    float bh = p[(size_t)3 * NA];

    const float* pc = p + (size_t)4 * NA;
    float best = -1.0f;
    int bl = 0;
#pragma unroll 16
    for (int r = 0; r < NCLS; ++r) {                  // 80 = 5 x 16
        float v = pc[(size_t)r * NA];
        bl = (v > best) ? r : bl;                     // first-max (strict >)
        best = fmaxf(v, best);
    }

    if (live) {
        float fx = bx * IMG_SZ, fy = by * IMG_SZ;
        float fw = bw * IMG_SZ, fh = bh * IMG_SZ;
        float hw = fw * 0.5f, hh = fh * 0.5f;
        boxes[(size_t)b * NA + a] = make_float4(fx - hw, fy - hh, fx + hw, fy + hh);
        float s = (best > CONF) ? best : -1.0f;
        u32 fb = __float_as_uint(s);
        u32 u = (fb & 0x80000000u) ? ~fb : (fb | 0x80000000u);
        keys[(size_t)b * NA + a] =
            ((u64)u << 21) | ((u64)(16383 - a) << 7) | (u64)bl;
    }
}

// ---- K2: radix-select + bitonic sort + gather + classify --------------------
// Merged 16-bit first pass (2 barriers) replaces d=3,d=2 byte passes; slot
// reductions replace smax/scnt atomics (2 barriers/pass instead of 4).
__global__ __launch_bounds__(NT, 4)
void select_sort_kernel(const u64* __restrict__ keys,
                        const float4* __restrict__ boxes,
                        u64* __restrict__ sortedk,
                        float4* __restrict__ gbox,
                        float4* __restrict__ goffb,
                        float* __restrict__ garea,
                        unsigned short* __restrict__ grank,
                        int* __restrict__ gccnt) {
    const int b = blockIdx.x;
    const int t = threadIdx.x;
    const int lane = t & 63, wid = t >> 6;

    __shared__ union {
        struct {                                    // phase A: select + sort
            u64 sk[2][NT];                          // 16 KB
            int hist[NCOPY * HPAD];                 // 8.3 KB
        } a;
        struct {                                    // phase B: classify
            u64 cmask2[NCLS][16];                   // 10 KB
        } bb;
    } u_s;
    __shared__ int selB, selK, hselS, cnt_s;
    __shared__ int wsum[16], woff[16];

    // ---- load this batch's keys (STATIC indexing; dummy 0-keys sort last) ----
    u64 kreg[KPT];
    const u64* kb = keys + (size_t)b * NA;
#pragma unroll
    for (int j = 0; j < KPT; ++j) {
        int i = t + j * NT;
        kreg[j] = (i < NA) ? kb[i] : 0ull;
    }

    u64 P = 0ull;
    int kk = TOPK;
    int nsel = 0;
    bool done = false;
    bool did16 = false;

    // ---- merged 16-bit shortcut pass over bits 52:37 (bytes d=3,d=2) ----
    {
        int dg[KPT];
        int mymax = -1;
#pragma unroll
        for (int j = 0; j < KPT; ++j) {
            dg[j] = (kreg[j] != 0ull) ? (int)((kreg[j] >> 37) & 0xFFFF) : -1;
            mymax = max(mymax, dg[j]);
        }
#pragma unroll
        for (int off = 32; off; off >>= 1)
            mymax = max(mymax, __shfl_down(mymax, off, 64));
        if (lane == 0) wsum[wid] = mymax;
        __syncthreads();
        int maxd = wsum[0];
#pragma unroll
        for (int q = 1; q < 16; ++q) maxd = max(maxd, wsum[q]);
        int myc = 0;
#pragma unroll
        for (int j = 0; j < KPT; ++j) myc += (dg[j] == maxd) ? 1 : 0;
#pragma unroll
        for (int off = 32; off; off >>= 1) myc += __shfl_down(myc, off, 64);
        if (lane == 0) woff[wid] = myc;
        __syncthreads();
        int cm = 0;
#pragma unroll
        for (int q = 0; q < 16; ++q) cm += woff[q];
        if (cm >= kk) {                 // all top-kk keys share this 16-bit prefix
            P = ((u64)maxd) << 37;
            nsel = cm;                  // TOPK - kk + cm with kk == TOPK
            did16 = true;
            done = (nsel <= NT);
        }
    }

    if (!done) {
        const int dstart = did16 ? 1 : 3;           // fallback covers full range
        for (int d = dstart; d >= 0; --d) {
            const int sh = 21 + 8 * d;
            const u64 hmask = (~0ull) << (sh + 8);
            int dig[KPT];
            int mymax = -1;
#pragma unroll
            for (int j = 0; j < KPT; ++j) {
                bool act = (((kreg[j] ^ P) & hmask) == 0ull) && (kreg[j] != 0ull);
                dig[j] = act ? (int)((kreg[j] >> sh) & 255) : -1;
                mymax = max(mymax, dig[j]);
            }
#pragma unroll
            for (int off = 32; off; off >>= 1)
                mymax = max(mymax, __shfl_down(mymax, off, 64));
            if (lane == 0) wsum[wid] = mymax;
            __syncthreads();                                      // S1
            int maxb = wsum[0];
#pragma unroll
            for (int q = 1; q < 16; ++q) maxb = max(maxb, wsum[q]);
            int myc = 0;
#pragma unroll
            for (int j = 0; j < KPT; ++j) myc += (dig[j] == maxb) ? 1 : 0;
#pragma unroll
            for (int off = 32; off; off >>= 1) myc += __shfl_down(myc, off, 64);
            if (lane == 0) woff[wid] = myc;
            __syncthreads();                                      // S2
            int cm = 0;
#pragma unroll
            for (int q = 0; q < 16; ++q) cm += woff[q];
            if (cm >= kk) {
                P |= ((u64)maxb) << sh;
                nsel = TOPK - kk + cm;
                if (nsel <= NT) break;
                continue;
            }
            // ---- fallback: full histogram pass ----
            for (int i = t; i < NCOPY * HPAD; i += NT) u_s.a.hist[i] = 0;
            __syncthreads();                                      // S3
            int* myh = u_s.a.hist + (wid & (NCOPY - 1)) * HPAD;
#pragma unroll
            for (int j = 0; j < KPT; ++j)
                if (dig[j] >= 0) atomicAdd(&myh[dig[j]], 1);
            __syncthreads();                                      // S4
            if (t < 64) {
                int h0 = 0, h1 = 0, h2 = 0, h3 = 0;
                for (int c = 0; c < NCOPY; ++c) {
                    const int* hp = u_s.a.hist + c * HPAD + 4 * t;
                    h0 += hp[0]; h1 += hp[1]; h2 += hp[2]; h3 += hp[3];
                }
                int s = h0 + h1 + h2 + h3;
                int S = s;
                #pragma unroll
                for (int off = 1; off < 64; off <<= 1) {
                    int o = __shfl_down(S, off, 64);
                    if (t + off < 64) S += o;
                }
                int Snext = S - s;
                int c3 = Snext + h3, c2 = c3 + h2, c1 = c2 + h1, c0 = c1 + h0;
                int cand = -1, above = 0;
                if (c0 >= kk) {
                    if      (c3 >= kk) { cand = 4 * t + 3; above = Snext; }
                    else if (c2 >= kk) { cand = 4 * t + 2; above = c3; }
                    else if (c1 >= kk) { cand = 4 * t + 1; above = c2; }
                    else               { cand = 4 * t;     above = c1; }
                }
                int pc = (cand < 0) ? 0 : (((cand + 1) << 16) | (kk - above));
                #pragma unroll
                for (int off = 32; off; off >>= 1)
                    pc = max(pc, __shfl_down(pc, off, 64));
                pc = __shfl(pc, 0, 64);
                int B = (pc >> 16) - 1;
                if (t == (B >> 2)) {
                    int m4 = B & 3;
                    selB = B;
                    selK = pc & 0xFFFF;
                    hselS = (m4 == 0) ? h0 : (m4 == 1) ? h1 : (m4 == 2) ? h2 : h3;
                }
            }
            __syncthreads();                                      // S5
            P |= ((u64)selB) << sh;
            kk = selK;
            nsel = TOPK - kk + hselS;
            if (nsel <= NT) break;
        }
    }

    // ---- compact the nsel (1000..1024) keys >= P ----
    __syncthreads();
    if (t == 0) cnt_s = 0;
    __syncthreads();
#pragma unroll
    for (int j = 0; j < KPT; ++j) {
        bool p = (kreg[j] >= P);
        u64 m = __ballot(p);
        int base = 0;
        if (lane == 0) base = atomicAdd(&cnt_s, (int)__popcll(m));
        base = __shfl(base, 0, 64);
        if (p) {
            int pos = base + (int)__popcll(m & ((1ull << lane) - 1ull));
            if (pos < NT) u_s.a.sk[0][pos] = kreg[j];
        }
    }
    if (t < NT - nsel) u_s.a.sk[0][nsel + t] = 0ull;
    __syncthreads();

    // ---- hybrid bitonic sort, descending ----
    u64 myk = u_s.a.sk[0][t];
    int buf = 1;
    for (int size = 2; size <= NT; size <<= 1) {
        bool up = ((t & size) == 0);
        for (int stride = size >> 1; stride; stride >>= 1) {
            u64 pk;
            if (stride >= 64) {
                u_s.a.sk[buf][t] = myk;
                __syncthreads();
                pk = u_s.a.sk[buf][t ^ stride];
                buf ^= 1;
            } else {
                pk = shflx64(myk, stride);
            }
            bool tlow = ((t & stride) == 0);
            u64 mn = (myk < pk) ? myk : pk;
            u64 mx = (myk < pk) ? pk : myk;
            myk = up ? (tlow ? mx : mn) : (tlow ? mn : mx);
        }
    }
    sortedk[(size_t)b * NT + t] = myk;

    __syncthreads();                     // done with sk -> reuse as cmask2
    for (int i = t; i < NCLS * 16; i += NT) ((u64*)u_s.bb.cmask2)[i] = 0ull;
    __syncthreads();

    // ---- gather + classify (label & anchor come from the key) ----
    int my_L = 0;
    float4 bx = make_float4(0.f, 0.f, 0.f, 0.f);
    if (t < TOPK) {
        int my_a = 16383 - (int)((myk >> 7) & 16383ull);
        my_L = (int)(myk & 127ull);
        bx = boxes[(size_t)b * NA + my_a];
        atomicOr(&u_s.bb.cmask2[my_L][t >> 6], 1ull << (t & 63));
    }
    __syncthreads();
    if (t < TOPK) {
        int w = t >> 6;
        int r = __popcll(u_s.bb.cmask2[my_L][w] & ((1ull << (t & 63)) - 1ull));
        for (int q = 0; q < w; ++q) r += __popcll(u_s.bb.cmask2[my_L][q]);
        gbox[(size_t)b * NT + t] = bx;
        if (r < 64) {
            float off = (float)my_L * MAX_WH;
            float ox0 = bx.x + off, oy0 = bx.y + off;
            float ox1 = bx.z + off, oy1 = bx.w + off;
            size_t ci = ((size_t)b * NCLS + my_L) * 64 + r;
            goffb[ci] = make_float4(ox0, oy0, ox1, oy1);
            garea[ci] = (ox1 - ox0) * (oy1 - oy0);   // ref: area on offset boxes
            grank[ci] = (unsigned short)t;
        }
    }
    if (t < NCLS) {
        int s = 0;
#pragma unroll
        for (int q = 0; q < 16; ++q) s += __popcll(u_s.bb.cmask2[t][q]);
        gccnt[(size_t)b * NCLS + t] = s;
    }
}

// ---- K3: fused NMS (16 waves x 5 classes) + epilogue ------------------------
__global__ __launch_bounds__(NT)
void nms_epi_kernel(const float4* __restrict__ goffb,
                    const float* __restrict__ garea,
                    const unsigned short* __restrict__ grank,
                    const int* __restrict__ gccnt,
                    const u64* __restrict__ sortedk,
                    const float4* __restrict__ gbox,
                    float* __restrict__ out) {
    const int b = blockIdx.x;
    const int t = threadIdx.x;
    const int lane = t & 63, wid = t >> 6;

    __shared__ unsigned char keep[NT];
    __shared__ int wsum[16], woff[16], ktot_s;

    keep[t] = 0;

    int cnts[5];
#pragma unroll
    for (int j = 0; j < 5; ++j)
        cnts[j] = gccnt[(size_t)b * NCLS + wid + 16 * j];

    u64 myk = sortedk[(size_t)b * NT + t];        // also used by epilogue
    __syncthreads();

    for (int j = 0; j < 5; ++j) {
        const int cc = wid + 16 * j;              // 16 waves x 5 -> classes 0..79
        const int n = cnts[j];
        if (n == 0) continue;
        if (n <= 64) {
            size_t ci = ((size_t)b * NCLS + cc) * 64 + lane;
            float4 bb = make_float4(0.f, 0.f, 0.f, 0.f);
            float ar = 0.f;
            int rk = 0;
            if (lane < n) { bb = goffb[ci]; ar = garea[ci]; rk = grank[ci]; }
            u64 colm = 0ull;
            for (int i = 0; i < n; ++i) {
                float hx0 = __shfl(bb.x, i, 64);
                float hy0 = __shfl(bb.y, i, 64);
                float hx1 = __shfl(bb.z, i, 64);
                float hy1 = __shfl(bb.w, i, 64);
                float ha  = __shfl(ar, i, 64);
                float lx = fmaxf(hx0, bb.x), ly = fmaxf(hy0, bb.y);
                float rx = fminf(hx1, bb.z), ry = fminf(hy1, bb.w);
                float w = fmaxf(rx - lx, 0.0f);
                float h = fmaxf(ry - ly, 0.0f);
                float inter = w * h;
                float denom = ha + ar;
                denom = denom - inter;
                denom = denom + 1e-7f;
                bool s = (lane > i) && (lane < n) && (inter / denom > IOU_T);
                colm |= ((u64)s) << i;
            }
            u64 alive = (n >= 64) ? ~0ull : ((1ull << n) - 1ull);
            for (int i = 0; i < n; ++i) {
                if (!((alive >> i) & 1ull)) continue;
                alive &= ~__ballot((colm >> i) & 1ull);
            }
            if (lane < n) keep[rk] = (unsigned char)((alive >> lane) & 1ull);
        } else if (lane == 0) {
            // exact serial fallback over rank order (never taken in practice);
            // recompute offset boxes from gbox + class (same FP ops as reference)
            const u64* skb = sortedk + (size_t)b * NT;
            const float4* gb = gbox + (size_t)b * NT;
            const float off = (float)cc * MAX_WH;
            u64 aliveW[16];
            for (int q = 0; q < 16; ++q) aliveW[q] = ~0ull;
            for (int i = 0; i < TOPK; ++i) {
                if ((int)(skb[i] & 127ull) != cc) continue;
                if (!((aliveW[i >> 6] >> (i & 63)) & 1ull)) continue;
                float4 g = gb[i];
                float ix0 = g.x + off, iy0 = g.y + off;
                float ix1 = g.z + off, iy1 = g.w + off;
                float ai = (ix1 - ix0) * (iy1 - iy0);
                for (int jj = i + 1; jj < TOPK; ++jj) {
                    if ((int)(skb[jj] & 127ull) != cc) continue;
                    if (!((aliveW[jj >> 6] >> (jj & 63)) & 1ull)) continue;
                    float4 h = gb[jj];
                    float jx0 = h.x + off, jy0 = h.y + off;
                    float jx1 = h.z + off, jy1 = h.w + off;
                    float aj = (jx1 - jx0) * (jy1 - jy0);
                    float lx = fmaxf(ix0, jx0), ly = fmaxf(iy0, jy0);
                    float rx = fminf(ix1, jx1), ry = fminf(iy1, jy1);
                    float ww = fmaxf(rx - lx, 0.0f);
                    float hh = fmaxf(ry - ly, 0.0f);
                    float inter = ww * hh;
                    float denom = ai + aj;
                    denom = denom - inter;
                    denom = denom + 1e-7f;
                    if (inter / denom > IOU_T) aliveW[jj >> 6] &= ~(1ull << (jj & 63));
                }
            }
            for (int i = 0; i < TOPK; ++i)
                if ((int)(skb[i] & 127ull) == cc)
                    keep[i] = (unsigned char)((aliveW[i >> 6] >> (i & 63)) & 1ull);
        }
    }
    __syncthreads();

    // ---- epilogue: rank-scan + output ----
    float sj = 0.0f;
    bool valid = false;
    if (t < TOPK) {
        u32 u = (u32)(myk >> 21);
        u32 fb = (u & 0x80000000u) ? (u ^ 0x80000000u) : ~u;
        sj = __uint_as_float(fb);
        valid = keep[t] && (sj > CONF);
    }
    u64 m = __ballot(valid);
    if (lane == 0) wsum[wid] = (int)__popcll(m);
    __syncthreads();
    if (wid == 0) {
        int v = (lane < 16) ? wsum[lane] : 0;
        #pragma unroll
        for (int o = 1; o < 16; o <<= 1) {
            int x = __shfl_up(v, o, 64);
            if (lane >= o) v += x;
        }
        if (lane < 16) woff[lane] = v - wsum[lane];
        if (lane == 15) ktot_s = v;
    }
    __syncthreads();
    int ktot = ktot_s;
    int rank = woff[wid] + (int)__popcll(m & ((1ull << lane) - 1ull));

    float* out_boxes = out;
    float* out_scores = out + (size_t)BATCH * MAXDET * 4;
    float* out_labels = out + (size_t)BATCH * MAXDET * 5;
    if (valid && rank < MAXDET) {
        float4 bx = gbox[(size_t)b * NT + t];
        float* ob = out_boxes + ((size_t)b * MAXDET + rank) * 4;
        ob[0] = bx.x; ob[1] = bx.y; ob[2] = bx.z; ob[3] = bx.w;
        out_scores[(size_t)b * MAXDET + rank] = sj;
        out_labels[(size_t)b * MAXDET + rank] = coco_map_f[(int)(myk & 127ull)];
    }
    if (t < MAXDET && t >= ktot) {
        float* ob = out_boxes + ((size_t)b * MAXDET + t) * 4;
        ob[0] = 0.0f; ob[1] = 0.0f; ob[2] = 0.0f; ob[3] = 0.0f;
        out_scores[(size_t)b * MAXDET + t] = 0.0f;
        out_labels[(size_t)b * MAXDET + t] = 0.0f;
    }
}

// ---------------------------------------------------------------------------
extern "C" void kernel_launch(void* const* d_in, const int* in_sizes, int n_in,
                              void* d_out, int out_size, void* d_ws, size_t ws_size,
                              hipStream_t stream) {
    const float* preds = (const float*)d_in[0];
    char* ws = (char*)d_ws;
    size_t off = 0;
    auto alloc = [&](size_t bytes) { char* p = ws + off; off += (bytes + 255) & ~(size_t)255; return p; };

    u64* keys            = (u64*)           alloc((size_t)BATCH * NA * 8);
    float4* boxes        = (float4*)        alloc((size_t)BATCH * NA * 16);
    u64* sortedk         = (u64*)           alloc((size_t)BATCH * NT * 8);
    float4* gbox         = (float4*)        alloc((size_t)BATCH * NT * 16);
    float4* goffb        = (float4*)        alloc((size_t)BATCH * NCLS * 64 * 16);
    float* garea         = (float*)         alloc((size_t)BATCH * NCLS * 64 * 4);
    unsigned short* grank= (unsigned short*)alloc((size_t)BATCH * NCLS * 64 * 2);
    int* gccnt           = (int*)           alloc((size_t)BATCH * NCLS * 4);
    float* out = (float*)d_out;

    dim3 dgrid((NA + 255) / 256, BATCH);           // 33 x 32
    decode_kernel<<<dgrid, 256, 0, stream>>>(preds, keys, boxes);
    select_sort_kernel<<<BATCH, NT, 0, stream>>>(keys, boxes, sortedk, gbox,
                                                 goffb, garea, grank, gccnt);
    nms_epi_kernel<<<BATCH, NT, 0, stream>>>(goffb, garea, grank, gccnt,
                                             sortedk, gbox, out);
}

// Round 7
// 163.177 us; speedup vs baseline: 1.1167x; 1.1167x over previous
//
#include <hip/hip_runtime.h>
#include <stdint.h>

typedef unsigned long long u64;
typedef unsigned int u32;

#define BATCH 32
#define NCH 84
#define NA 8400
#define NCLS 80
#define TOPK 1000
#define MAXDET 300
#define CONF 0.25f
#define IOU_T 0.7f
#define MAX_WH 7680.0f
#define IMG_SZ 640.0f
#define NT 1024
#define KPT 9            // ceil(NA / NT)
#define NCOPY 8          // privatized histogram copies (fallback path)
#define HPAD 260         // 16B-aligned rows, bank-staggered copies

__device__ __constant__ float coco_map_f[NCLS] = {
    1,2,3,4,5,6,7,8,9,10,11,13,14,15,16,17,18,19,20,21,22,23,24,25,27,28,
    31,32,33,34,35,36,37,38,39,40,41,42,43,44,46,47,48,49,50,51,52,53,54,
    55,56,57,58,59,60,61,62,63,64,65,67,70,72,73,74,75,76,77,78,79,80,81,
    82,84,85,86,87,88,89,90};

__device__ inline u64 shflx64(u64 v, int m) {
    int lo = __shfl_xor((int)(u32)(v & 0xFFFFFFFFull), m, 64);
    int hi = __shfl_xor((int)(u32)(v >> 32), m, 64);
    return ((u64)(u32)hi << 32) | (u32)lo;
}

// ---- K1: decode, direct coalesced reads (no LDS) ----------------------------
// key = score_bits<<21 | (16383-a)<<7 | label   (order: score desc, anchor asc)
__global__ __launch_bounds__(256)
void decode_kernel(const float* __restrict__ preds,
                   u64* __restrict__ keys,
                   float4* __restrict__ boxes) {
    const int b = blockIdx.y;
    const int a = blockIdx.x * 256 + threadIdx.x;
    const bool live = (a < NA);
    const int ac = live ? a : (NA - 1);               // clamp: keep loads in-bounds
    const float* p = preds + (size_t)b * NCH * NA + ac;

    float bx = p[0];
    float by = p[(size_t)1 * NA];
    float bw = p[(size_t)2 * NA];
    float bh = p[(size_t)3 * NA];

    const float* pc = p + (size_t)4 * NA;
    float best = -1.0f;
    int bl = 0;
#pragma unroll 16
    for (int r = 0; r < NCLS; ++r) {                  // 80 = 5 x 16
        float v = pc[(size_t)r * NA];
        bl = (v > best) ? r : bl;                     // first-max (strict >)
        best = fmaxf(v, best);
    }

    if (live) {
        float fx = bx * IMG_SZ, fy = by * IMG_SZ;
        float fw = bw * IMG_SZ, fh = bh * IMG_SZ;
        float hw = fw * 0.5f, hh = fh * 0.5f;
        boxes[(size_t)b * NA + a] = make_float4(fx - hw, fy - hh, fx + hw, fy + hh);
        float s = (best > CONF) ? best : -1.0f;
        u32 fb = __float_as_uint(s);
        u32 u = (fb & 0x80000000u) ? ~fb : (fb | 0x80000000u);
        keys[(size_t)b * NA + a] =
            ((u64)u << 21) | ((u64)(16383 - a) << 7) | (u64)bl;
    }
}

// ---- K2: radix-select + bitonic sort + gather + classify --------------------
// r5 structure; ONLY change: merged 16-bit first pass (2 barriers, covers the
// two degenerate byte passes) + slot reductions (2 barriers/pass vs 4).
__global__ __launch_bounds__(NT, 4)
void select_sort_kernel(const u64* __restrict__ keys,
                        const float4* __restrict__ boxes,
                        u64* __restrict__ sortedk,
                        float4* __restrict__ gbox,
                        float4* __restrict__ goffb,
                        float* __restrict__ garea,
                        unsigned short* __restrict__ grank,
                        int* __restrict__ gccnt) {
    const int b = blockIdx.x;
    const int t = threadIdx.x;
    const int lane = t & 63, wid = t >> 6;

    __shared__ union {
        struct {                                    // phase A: select + sort
            u64 sk[2][NT];                          // 16 KB
            int hist[NCOPY * HPAD];                 // 8.3 KB
        } a;
        struct {                                    // phase B: classify
            u64 cmask2[NCLS][16];                   // 10 KB
        } bb;
    } u_s;
    __shared__ int selB, selK, hselS, cnt_s;
    __shared__ int wsum[16], woff[16];

    // ---- load this batch's keys (STATIC indexing; dummy 0-keys sort last) ----
    u64 kreg[KPT];
    const u64* kb = keys + (size_t)b * NA;
#pragma unroll
    for (int j = 0; j < KPT; ++j) {
        int i = t + j * NT;
        kreg[j] = (i < NA) ? kb[i] : 0ull;
    }

    u64 P = 0ull;
    int kk = TOPK;
    int nsel = 0;
    bool done = false;
    bool did16 = false;

    // ---- merged 16-bit shortcut pass over bits 52:37 (bytes d=3,d=2) ----
    {
        int dg[KPT];
        int mymax = -1;
#pragma unroll
        for (int j = 0; j < KPT; ++j) {
            dg[j] = (kreg[j] != 0ull) ? (int)((kreg[j] >> 37) & 0xFFFF) : -1;
            mymax = max(mymax, dg[j]);
        }
#pragma unroll
        for (int off = 32; off; off >>= 1)
            mymax = max(mymax, __shfl_down(mymax, off, 64));
        if (lane == 0) wsum[wid] = mymax;
        __syncthreads();
        int maxd = wsum[0];
#pragma unroll
        for (int q = 1; q < 16; ++q) maxd = max(maxd, wsum[q]);
        int myc = 0;
#pragma unroll
        for (int j = 0; j < KPT; ++j) myc += (dg[j] == maxd) ? 1 : 0;
#pragma unroll
        for (int off = 32; off; off >>= 1) myc += __shfl_down(myc, off, 64);
        if (lane == 0) woff[wid] = myc;
        __syncthreads();
        int cm = 0;
#pragma unroll
        for (int q = 0; q < 16; ++q) cm += woff[q];
        if (cm >= kk) {                 // all top-kk keys share this 16-bit prefix
            P = ((u64)maxd) << 37;
            nsel = cm;                  // TOPK - kk + cm with kk == TOPK
            did16 = true;
            done = (nsel <= NT);
        }
    }

    if (!done) {
        const int dstart = did16 ? 1 : 3;           // fallback covers full range
        for (int d = dstart; d >= 0; --d) {
            const int sh = 21 + 8 * d;
            const u64 hmask = (~0ull) << (sh + 8);
            int dig[KPT];
            int mymax = -1;
#pragma unroll
            for (int j = 0; j < KPT; ++j) {
                bool act = (((kreg[j] ^ P) & hmask) == 0ull) && (kreg[j] != 0ull);
                dig[j] = act ? (int)((kreg[j] >> sh) & 255) : -1;
                mymax = max(mymax, dig[j]);
            }
#pragma unroll
            for (int off = 32; off; off >>= 1)
                mymax = max(mymax, __shfl_down(mymax, off, 64));
            if (lane == 0) wsum[wid] = mymax;
            __syncthreads();                                      // S1
            int maxb = wsum[0];
#pragma unroll
            for (int q = 1; q < 16; ++q) maxb = max(maxb, wsum[q]);
            int myc = 0;
#pragma unroll
            for (int j = 0; j < KPT; ++j) myc += (dig[j] == maxb) ? 1 : 0;
#pragma unroll
            for (int off = 32; off; off >>= 1) myc += __shfl_down(myc, off, 64);
            if (lane == 0) woff[wid] = myc;
            __syncthreads();                                      // S2
            int cm = 0;
#pragma unroll
            for (int q = 0; q < 16; ++q) cm += woff[q];
            if (cm >= kk) {
                P |= ((u64)maxb) << sh;
                nsel = TOPK - kk + cm;
                if (nsel <= NT) break;
                continue;
            }
            // ---- fallback: full histogram pass ----
            for (int i = t; i < NCOPY * HPAD; i += NT) u_s.a.hist[i] = 0;
            __syncthreads();                                      // S3
            int* myh = u_s.a.hist + (wid & (NCOPY - 1)) * HPAD;
#pragma unroll
            for (int j = 0; j < KPT; ++j)
                if (dig[j] >= 0) atomicAdd(&myh[dig[j]], 1);
            __syncthreads();                                      // S4
            if (t < 64) {
                int h0 = 0, h1 = 0, h2 = 0, h3 = 0;
                for (int c = 0; c < NCOPY; ++c) {
                    const int* hp = u_s.a.hist + c * HPAD + 4 * t;
                    h0 += hp[0]; h1 += hp[1]; h2 += hp[2]; h3 += hp[3];
                }
                int s = h0 + h1 + h2 + h3;
                int S = s;
                #pragma unroll
                for (int off = 1; off < 64; off <<= 1) {
                    int o = __shfl_down(S, off, 64);
                    if (t + off < 64) S += o;
                }
                int Snext = S - s;
                int c3 = Snext + h3, c2 = c3 + h2, c1 = c2 + h1, c0 = c1 + h0;
                int cand = -1, above = 0;
                if (c0 >= kk) {
                    if      (c3 >= kk) { cand = 4 * t + 3; above = Snext; }
                    else if (c2 >= kk) { cand = 4 * t + 2; above = c3; }
                    else if (c1 >= kk) { cand = 4 * t + 1; above = c2; }
                    else               { cand = 4 * t;     above = c1; }
                }
                int pc = (cand < 0) ? 0 : (((cand + 1) << 16) | (kk - above));
                #pragma unroll
                for (int off = 32; off; off >>= 1)
                    pc = max(pc, __shfl_down(pc, off, 64));
                pc = __shfl(pc, 0, 64);
                int B = (pc >> 16) - 1;
                if (t == (B >> 2)) {
                    int m4 = B & 3;
                    selB = B;
                    selK = pc & 0xFFFF;
                    hselS = (m4 == 0) ? h0 : (m4 == 1) ? h1 : (m4 == 2) ? h2 : h3;
                }
            }
            __syncthreads();                                      // S5
            P |= ((u64)selB) << sh;
            kk = selK;
            nsel = TOPK - kk + hselS;
            if (nsel <= NT) break;
        }
    }

    // ---- compact the nsel (1000..1024) keys >= P ----
    __syncthreads();
    if (t == 0) cnt_s = 0;
    __syncthreads();
#pragma unroll
    for (int j = 0; j < KPT; ++j) {
        bool p = (kreg[j] >= P);
        u64 m = __ballot(p);
        int base = 0;
        if (lane == 0) base = atomicAdd(&cnt_s, (int)__popcll(m));
        base = __shfl(base, 0, 64);
        if (p) {
            int pos = base + (int)__popcll(m & ((1ull << lane) - 1ull));
            if (pos < NT) u_s.a.sk[0][pos] = kreg[j];
        }
    }
    if (t < NT - nsel) u_s.a.sk[0][nsel + t] = 0ull;
    __syncthreads();

    // ---- hybrid bitonic sort, descending ----
    u64 myk = u_s.a.sk[0][t];
    int buf = 1;
    for (int size = 2; size <= NT; size <<= 1) {
        bool up = ((t & size) == 0);
        for (int stride = size >> 1; stride; stride >>= 1) {
            u64 pk;
            if (stride >= 64) {
                u_s.a.sk[buf][t] = myk;
                __syncthreads();
                pk = u_s.a.sk[buf][t ^ stride];
                buf ^= 1;
            } else {
                pk = shflx64(myk, stride);
            }
            bool tlow = ((t & stride) == 0);
            u64 mn = (myk < pk) ? myk : pk;
            u64 mx = (myk < pk) ? pk : myk;
            myk = up ? (tlow ? mx : mn) : (tlow ? mn : mx);
        }
    }
    sortedk[(size_t)b * NT + t] = myk;

    __syncthreads();                     // done with sk -> reuse as cmask2
    for (int i = t; i < NCLS * 16; i += NT) ((u64*)u_s.bb.cmask2)[i] = 0ull;
    __syncthreads();

    // ---- gather + classify (label & anchor come from the key) ----
    int my_L = 0;
    float4 bx = make_float4(0.f, 0.f, 0.f, 0.f);
    if (t < TOPK) {
        int my_a = 16383 - (int)((myk >> 7) & 16383ull);
        my_L = (int)(myk & 127ull);
        bx = boxes[(size_t)b * NA + my_a];
        atomicOr(&u_s.bb.cmask2[my_L][t >> 6], 1ull << (t & 63));
    }
    __syncthreads();
    if (t < TOPK) {
        int w = t >> 6;
        int r = __popcll(u_s.bb.cmask2[my_L][w] & ((1ull << (t & 63)) - 1ull));
        for (int q = 0; q < w; ++q) r += __popcll(u_s.bb.cmask2[my_L][q]);
        gbox[(size_t)b * NT + t] = bx;
        if (r < 64) {
            float off = (float)my_L * MAX_WH;
            float ox0 = bx.x + off, oy0 = bx.y + off;
            float ox1 = bx.z + off, oy1 = bx.w + off;
            size_t ci = ((size_t)b * NCLS + my_L) * 64 + r;
            goffb[ci] = make_float4(ox0, oy0, ox1, oy1);
            garea[ci] = (ox1 - ox0) * (oy1 - oy0);   // ref: area on offset boxes
            grank[ci] = (unsigned short)t;
        }
    }
    if (t < NCLS) {
        int s = 0;
#pragma unroll
        for (int q = 0; q < 16; ++q) s += __popcll(u_s.bb.cmask2[t][q]);
        gccnt[(size_t)b * NCLS + t] = s;
    }
}

// ---- K3: NMS, one (class,batch) per 64-thread block (2560 blocks) -----------
__global__ __launch_bounds__(64)
void nms_kernel(const float4* __restrict__ goffb,
                const float* __restrict__ garea,
                const unsigned short* __restrict__ grank,
                const int* __restrict__ gccnt,
                const u64* __restrict__ sortedk,
                const float4* __restrict__ gbox,
                unsigned char* __restrict__ keepg) {
    const int c = blockIdx.x;
    const int b = blockIdx.y;
    const int lane = threadIdx.x;
    const int n = gccnt[(size_t)b * NCLS + c];
    if (n == 0) return;

    if (n <= 64) {
        size_t ci = ((size_t)b * NCLS + c) * 64 + lane;
        float4 bb = make_float4(0.f, 0.f, 0.f, 0.f);
        float ar = 0.f;
        int rk = 0;
        if (lane < n) { bb = goffb[ci]; ar = garea[ci]; rk = grank[ci]; }
        // phase 1: colmask (independent iterations)
        u64 colm = 0ull;
        for (int i = 0; i < n; ++i) {
            float hx0 = __shfl(bb.x, i, 64);
            float hy0 = __shfl(bb.y, i, 64);
            float hx1 = __shfl(bb.z, i, 64);
            float hy1 = __shfl(bb.w, i, 64);
            float ha  = __shfl(ar, i, 64);
            float lx = fmaxf(hx0, bb.x), ly = fmaxf(hy0, bb.y);
            float rx = fminf(hx1, bb.z), ry = fminf(hy1, bb.w);
            float w = fmaxf(rx - lx, 0.0f);
            float h = fmaxf(ry - ly, 0.0f);
            float inter = w * h;
            float denom = ha + ar;
            denom = denom - inter;
            denom = denom + 1e-7f;
            bool s = (lane > i) && (lane < n) && (inter / denom > IOU_T);
            colm |= ((u64)s) << i;
        }
        // phase 2: resolve
        u64 alive = (n >= 64) ? ~0ull : ((1ull << n) - 1ull);
        for (int i = 0; i < n; ++i) {
            if (!((alive >> i) & 1ull)) continue;
            alive &= ~__ballot((colm >> i) & 1ull);
        }
        if (lane < n) keepg[(size_t)b * NT + rk] = (unsigned char)((alive >> lane) & 1ull);
    } else if (lane == 0) {
        // exact serial fallback over rank order (never taken in practice);
        // recompute offset boxes from gbox + class (same FP ops as reference)
        const u64* skb = sortedk + (size_t)b * NT;
        const float4* gb = gbox + (size_t)b * NT;
        const float off = (float)c * MAX_WH;
        u64 aliveW[16];
        for (int q = 0; q < 16; ++q) aliveW[q] = ~0ull;
        for (int i = 0; i < TOPK; ++i) {
            if ((int)(skb[i] & 127ull) != c) continue;
            if (!((aliveW[i >> 6] >> (i & 63)) & 1ull)) continue;
            float4 g = gb[i];
            float ix0 = g.x + off, iy0 = g.y + off;
            float ix1 = g.z + off, iy1 = g.w + off;
            float ai = (ix1 - ix0) * (iy1 - iy0);
            for (int jj = i + 1; jj < TOPK; ++jj) {
                if ((int)(skb[jj] & 127ull) != c) continue;
                if (!((aliveW[jj >> 6] >> (jj & 63)) & 1ull)) continue;
                float4 h = gb[jj];
                float jx0 = h.x + off, jy0 = h.y + off;
                float jx1 = h.z + off, jy1 = h.w + off;
                float aj = (jx1 - jx0) * (jy1 - jy0);
                float lx = fmaxf(ix0, jx0), ly = fmaxf(iy0, jy0);
                float rx = fminf(ix1, jx1), ry = fminf(iy1, jy1);
                float ww = fmaxf(rx - lx, 0.0f);
                float hh = fmaxf(ry - ly, 0.0f);
                float inter = ww * hh;
                float denom = ai + aj;
                denom = denom - inter;
                denom = denom + 1e-7f;
                if (inter / denom > IOU_T) aliveW[jj >> 6] &= ~(1ull << (jj & 63));
            }
        }
        for (int i = 0; i < TOPK; ++i)
            if ((int)(skb[i] & 127ull) == c)
                keepg[(size_t)b * NT + i] = (unsigned char)((aliveW[i >> 6] >> (i & 63)) & 1ull);
    }
}

// ---- K4: epilogue — rank-scan + output --------------------------------------
__global__ __launch_bounds__(NT)
void epilogue_kernel(const u64* __restrict__ sortedk,
                     const unsigned char* __restrict__ keepg,
                     const float4* __restrict__ gbox,
                     float* __restrict__ out) {
    const int b = blockIdx.x;
    const int t = threadIdx.x;
    const int lane = t & 63, wid = t >> 6;
    __shared__ int wsum[16], woff[16], ktot_s;

    u64 myk = sortedk[(size_t)b * NT + t];
    bool valid = false;
    float sj = 0.0f;
    if (t < TOPK) {
        u32 u = (u32)(myk >> 21);
        u32 fb = (u & 0x80000000u) ? (u ^ 0x80000000u) : ~u;
        sj = __uint_as_float(fb);
        valid = keepg[(size_t)b * NT + t] && (sj > CONF);
    }
    u64 m = __ballot(valid);
    if (lane == 0) wsum[wid] = (int)__popcll(m);
    __syncthreads();
    if (wid == 0) {
        int v = (lane < 16) ? wsum[lane] : 0;
        #pragma unroll
        for (int off = 1; off < 16; off <<= 1) {
            int o = __shfl_up(v, off, 64);
            if (lane >= off) v += o;
        }
        if (lane < 16) woff[lane] = v - wsum[lane];
        if (lane == 15) ktot_s = v;
    }
    __syncthreads();
    int ktot = ktot_s;
    int rank = woff[wid] + (int)__popcll(m & ((1ull << lane) - 1ull));

    float* out_boxes = out;
    float* out_scores = out + (size_t)BATCH * MAXDET * 4;
    float* out_labels = out + (size_t)BATCH * MAXDET * 5;
    if (valid && rank < MAXDET) {
        float4 bx = gbox[(size_t)b * NT + t];
        float* ob = out_boxes + ((size_t)b * MAXDET + rank) * 4;
        ob[0] = bx.x; ob[1] = bx.y; ob[2] = bx.z; ob[3] = bx.w;
        out_scores[(size_t)b * MAXDET + rank] = sj;
        out_labels[(size_t)b * MAXDET + rank] = coco_map_f[(int)(myk & 127ull)];
    }
    if (t < MAXDET && t >= ktot) {
        float* ob = out_boxes + ((size_t)b * MAXDET + t) * 4;
        ob[0] = 0.0f; ob[1] = 0.0f; ob[2] = 0.0f; ob[3] = 0.0f;
        out_scores[(size_t)b * MAXDET + t] = 0.0f;
        out_labels[(size_t)b * MAXDET + t] = 0.0f;
    }
}

// ---------------------------------------------------------------------------
extern "C" void kernel_launch(void* const* d_in, const int* in_sizes, int n_in,
                              void* d_out, int out_size, void* d_ws, size_t ws_size,
                              hipStream_t stream) {
    const float* preds = (const float*)d_in[0];
    char* ws = (char*)d_ws;
    size_t off = 0;
    auto alloc = [&](size_t bytes) { char* p = ws + off; off += (bytes + 255) & ~(size_t)255; return p; };

    u64* keys            = (u64*)           alloc((size_t)BATCH * NA * 8);
    float4* boxes        = (float4*)        alloc((size_t)BATCH * NA * 16);
    u64* sortedk         = (u64*)           alloc((size_t)BATCH * NT * 8);
    float4* gbox         = (float4*)        alloc((size_t)BATCH * NT * 16);
    float4* goffb        = (float4*)        alloc((size_t)BATCH * NCLS * 64 * 16);
    float* garea         = (float*)         alloc((size_t)BATCH * NCLS * 64 * 4);
    unsigned short* grank= (unsigned short*)alloc((size_t)BATCH * NCLS * 64 * 2);
    int* gccnt           = (int*)           alloc((size_t)BATCH * NCLS * 4);
    unsigned char* keepg = (unsigned char*) alloc((size_t)BATCH * NT);
    float* out = (float*)d_out;

    dim3 dgrid((NA + 255) / 256, BATCH);           // 33 x 32
    decode_kernel<<<dgrid, 256, 0, stream>>>(preds, keys, boxes);
    select_sort_kernel<<<BATCH, NT, 0, stream>>>(keys, boxes, sortedk, gbox,
                                                 goffb, garea, grank, gccnt);
    dim3 ngrid(NCLS, BATCH);                       // 80 x 32
    nms_kernel<<<ngrid, 64, 0, stream>>>(goffb, garea, grank, gccnt,
                                         sortedk, gbox, keepg);
    epilogue_kernel<<<BATCH, NT, 0, stream>>>(sortedk, keepg, gbox, out);
}